// Round 12
// baseline (389.309 us; speedup 1.0000x reference)
//
#include <hip/hip_runtime.h>
#include <stdint.h>

#define B_ROWS 16384
#define IN_DIM 1024
#define H_DIM  1024
#define KDIM   2048   // I + H
#define NDIM   4096   // 4*H
#define LN_EPSF 1e-5f

typedef unsigned short u16;
typedef float  f32x4  __attribute__((ext_vector_type(4)));
typedef float  fv4    __attribute__((ext_vector_type(4)));
typedef __bf16 bf16x8 __attribute__((ext_vector_type(8)));
typedef u16    u16x4  __attribute__((ext_vector_type(4)));
typedef u16    u16x8  __attribute__((ext_vector_type(8)));

__device__ __forceinline__ u16 f2bf(float f) {
  unsigned u = __float_as_uint(f);
  u += 0x7FFFu + ((u >> 16) & 1u);   // RNE
  return (u16)(u >> 16);
}
__device__ __forceinline__ float bf2f(u16 s) {
  return __uint_as_float(((unsigned)s) << 16);
}

#define GLOAD_LDS16(gp, lp) __builtin_amdgcn_global_load_lds( \
    (__attribute__((address_space(1))) void*)(gp),            \
    (__attribute__((address_space(3))) void*)(lp), 16, 0, 0)

// ---------------- cast kernels ----------------
__global__ __launch_bounds__(256) void cast_concat(
    const float* __restrict__ x, const float* __restrict__ h,
    u16* __restrict__ cat) {
  int idx = blockIdx.x * 256 + threadIdx.x;
  long base = (long)idx * 8;
  int  c = (int)(base & (KDIM - 1));
  long b = base >> 11;
  const float* src = (c < IN_DIM) ? (x + b * IN_DIM + c)
                                  : (h + b * H_DIM + (c - IN_DIM));
  fv4 v0 = *(const fv4*)(src);
  fv4 v1 = *(const fv4*)(src + 4);
  u16x8 o;
  o[0]=f2bf(v0[0]); o[1]=f2bf(v0[1]); o[2]=f2bf(v0[2]); o[3]=f2bf(v0[3]);
  o[4]=f2bf(v1[0]); o[5]=f2bf(v1[1]); o[6]=f2bf(v1[2]); o[7]=f2bf(v1[3]);
  *(u16x8*)(cat + base) = o;
}

__global__ __launch_bounds__(256) void cast_plain(
    const float* __restrict__ w, u16* __restrict__ wb) {
  int idx = blockIdx.x * 256 + threadIdx.x;
  long base = (long)idx * 8;
  fv4 v0 = *(const fv4*)(w + base);
  fv4 v1 = *(const fv4*)(w + base + 4);
  u16x8 o;
  o[0]=f2bf(v0[0]); o[1]=f2bf(v0[1]); o[2]=f2bf(v0[2]); o[3]=f2bf(v0[3]);
  o[4]=f2bf(v1[0]); o[5]=f2bf(v1[1]); o[6]=f2bf(v1[2]); o[7]=f2bf(v1[3]);
  *(u16x8*)(wb + base) = o;
}

// ---------------- GEMM: C[M][N] = A[M][K] * B[N][K]^T ----------------
// R12: 8-phase with ONE-PHASE-AHEAD reads (m201 stagger). 256x256, BK=64,
// 8 waves (2Mx4N). Phase p reads operands for p+1 into rotating aP/aQ/bP/bQ;
// lgkmcnt(R_issued) before MFMA (older reads done); 1 barrier/phase;
// vmcnt(4) before the P2/P6 end-barriers (slot residency, cross-wave).
// Stage ledger P1..P8: A0p02,B0p01,B0p23,A0p13,A1p02,B1p01,B1p23,A1p13.

#define STA(S_, P_, T_) GLOAD_LDS16(pA + (size_t)(P_) * 64 * KDIM + (T_) * 64, \
                                    &LA[S_][(P_) * 4096 + tid * 8])
#define STB(S_, P_, T_) GLOAD_LDS16(pB + (size_t)(P_) * 64 * KDIM + (T_) * 64, \
                                    &LB[S_][(P_) * 4096 + tid * 8])

#define RDA(S_, D_, MB_) { const u16* ap_ = &LA[S_][abase + ((MB_) >> 2) * 4096]; \
  _Pragma("unroll") for (int i_ = 0; i_ < 4; ++i_) {                          \
    D_[i_][0] = *(const bf16x8*)(ap_ + i_ * 1024 + kk0);                      \
    D_[i_][1] = *(const bf16x8*)(ap_ + i_ * 1024 + kk1); } }

#define RDB(S_, D_, NB_) { const u16* bp_ = &LB[S_][bbase + (NB_) * 1024];    \
  _Pragma("unroll") for (int i_ = 0; i_ < 2; ++i_) {                          \
    D_[i_][0] = *(const bf16x8*)(bp_ + i_ * 1024 + kk0);                      \
    D_[i_][1] = *(const bf16x8*)(bp_ + i_ * 1024 + kk1); } }

#define MQ(MB_, A_, NB_, B_)                                                  \
  _Pragma("unroll") for (int m_ = 0; m_ < 4; ++m_)                            \
  _Pragma("unroll") for (int n_ = 0; n_ < 2; ++n_) {                          \
    acc[(MB_) + m_][(NB_) + n_] = __builtin_amdgcn_mfma_f32_16x16x32_bf16(    \
        A_[m_][0], B_[n_][0], acc[(MB_) + m_][(NB_) + n_], 0, 0, 0);          \
    acc[(MB_) + m_][(NB_) + n_] = __builtin_amdgcn_mfma_f32_16x16x32_bf16(    \
        A_[m_][1], B_[n_][1], acc[(MB_) + m_][(NB_) + n_], 0, 0, 0); }

#define PHW(N_)                                                               \
  asm volatile("s_waitcnt lgkmcnt(" #N_ ")" ::: "memory");                    \
  __builtin_amdgcn_sched_barrier(0);                                          \
  __builtin_amdgcn_s_setprio(1);

#define PHE                                                                   \
  __builtin_amdgcn_s_setprio(0);                                              \
  __builtin_amdgcn_sched_barrier(0);                                          \
  __builtin_amdgcn_s_barrier();

__global__ __launch_bounds__(512, 2) void gemm_bt(
    const u16* __restrict__ A,   // [B_ROWS][KDIM]
    const u16* __restrict__ Bw,  // [NDIM][KDIM]
    u16* __restrict__ C) {       // [B_ROWS][NDIM] bf16
  __shared__ u16 LA[2][16384];   // [slot][piece*4096], piece = [64][64]
  __shared__ u16 LB[2][16384];

  const int tid  = threadIdx.x;
  const int lane = tid & 63;
  const int wave = tid >> 6;
  const int wm   = wave >> 2;    // 0..1
  const int wn   = wave & 3;     // 0..3
  const int r    = lane & 15;
  const int g    = lane >> 4;    // 0..3

  // col-fast XCD walk
  const int bid = blockIdx.x;
  const int xcd = bid & 7;
  const int k_  = bid >> 3;            // 0..127
  const int row0 = (xcd * 8 + (k_ >> 4)) * 256;
  const int col0 = (k_ & 15) * 256;

  // stage addressing (chunk swizzle): phys chunk tid <- logical l
  const int l    = tid ^ ((tid >> 3) & 7);
  const int srow = l >> 3;
  const int skc  = (l & 7) * 8;
  const u16* pA = A  + (size_t)(row0 + srow) * KDIM + skc;
  const u16* pB = Bw + (size_t)(col0 + srow) * KDIM + skc;

  // read addressing (u16 units) with read-side swizzle
  const int rx   = r & 7;
  const int kk0  = ((g    ) ^ rx) << 3;
  const int kk1  = ((4 | g) ^ rx) << 3;
  const int abase = wm * 8192 + r * 64;
  const int bbase = wn * 4096 + r * 64;

  f32x4 acc[8][4] = {};
  bf16x8 aP[4][2], aQ[4][2], bP[2][2], bQ[2][2];

  // ---- prologue: stage tile0 (slot0, 8 gloads) then tile1 (slot1, 8) ----
  STA(0, 0, 0); STA(0, 2, 0); STB(0, 0, 0); STB(0, 1, 0);
  STB(0, 2, 0); STB(0, 3, 0); STA(0, 1, 0); STA(0, 3, 0);
  STA(1, 0, 1); STA(1, 2, 1); STB(1, 0, 1); STB(1, 1, 1);
  STB(1, 2, 1); STB(1, 3, 1); STA(1, 1, 1); STA(1, 3, 1);
  asm volatile("s_waitcnt vmcnt(8)" ::: "memory");  // tile0 landed
  __builtin_amdgcn_s_barrier();
  RDA(0, aP, 0);   // A-u mb0
  RDB(0, bP, 0);   // B-u n01

  for (int it = 0; it < 16; ++it) {
    const int u = 2 * it;
    const bool st = it < 15;

    // P1: rd bQ <- B-u n23 ; st A0p0,2(u') ; MQ(u, mb0, n01)
    RDB(0, bQ, 2);
    if (st) { STA(0, 0, u + 2); STA(0, 2, u + 2); }
    PHW(4); MQ(0, aP, 0, bP); PHE;

    // P2: rd aQ <- A-u mb4 ; st B0p0,1 ; MQ(u, mb0, n23) ; vmcnt -> v resident
    RDA(0, aQ, 4);
    if (st) { STB(0, 0, u + 2); STB(0, 1, u + 2); }
    PHW(8); MQ(0, aP, 2, bQ);
    __builtin_amdgcn_s_setprio(0);
    __builtin_amdgcn_sched_barrier(0);
    if (st) { asm volatile("s_waitcnt vmcnt(4)" ::: "memory"); }
    else    { asm volatile("s_waitcnt vmcnt(0)" ::: "memory"); }
    __builtin_amdgcn_s_barrier();

    // P3: rd aP <- A-v mb0 ; st B0p2,3 ; MQ(u, mb4, n01)
    RDA(1, aP, 0);
    if (st) { STB(0, 2, u + 2); STB(0, 3, u + 2); }
    PHW(8); MQ(4, aQ, 0, bP); PHE;

    // P4: rd bP <- B-v n01 ; st A0p1,3 ; MQ(u, mb4, n23)
    RDB(1, bP, 0);
    if (st) { STA(0, 1, u + 2); STA(0, 3, u + 2); }
    PHW(4); MQ(4, aQ, 2, bQ); PHE;

    // P5: rd bQ <- B-v n23 ; st A1p0,2(v') ; MQ(v, mb0, n01)
    RDB(1, bQ, 2);
    if (st) { STA(1, 0, u + 3); STA(1, 2, u + 3); }
    PHW(4); MQ(0, aP, 0, bP); PHE;

    // P6: rd aQ <- A-v mb4 ; st B1p0,1 ; MQ(v, mb0, n23) ; vmcnt -> u' resident
    RDA(1, aQ, 4);
    if (st) { STB(1, 0, u + 3); STB(1, 1, u + 3); }
    PHW(8); MQ(0, aP, 2, bQ);
    __builtin_amdgcn_s_setprio(0);
    __builtin_amdgcn_sched_barrier(0);
    if (st) { asm volatile("s_waitcnt vmcnt(4)" ::: "memory"); }
    else    { asm volatile("s_waitcnt vmcnt(0)" ::: "memory"); }
    __builtin_amdgcn_s_barrier();

    // P7: rd aP <- A-u' mb0 ; st B1p2,3 ; MQ(v, mb4, n01)
    if (st) {
      RDA(0, aP, 0);
      STB(1, 2, u + 3); STB(1, 3, u + 3);
      PHW(8);
    } else {
      PHW(0);
    }
    MQ(4, aQ, 0, bP); PHE;

    // P8: rd bP <- B-u' n01 ; st A1p1,3 ; MQ(v, mb4, n23)
    if (st) {
      RDB(0, bP, 0);
      STA(1, 1, u + 3); STA(1, 3, u + 3);
      PHW(4);
    } else {
      PHW(0);
    }
    MQ(4, aQ, 2, bQ); PHE;
  }

  // ---- epilogue: C/D layout col=lane&15, row=(lane>>4)*4+reg ----
#pragma unroll
  for (int m = 0; m < 8; ++m)
#pragma unroll
    for (int n = 0; n < 4; ++n)
#pragma unroll
      for (int q = 0; q < 4; ++q) {
        const int rr = row0 + wm * 128 + m * 16 + g * 4 + q;
        const int cc = col0 + wn * 64 + n * 16 + r;
        C[(size_t)rr * NDIM + cc] = f2bf(acc[m][n][q]);
      }
}

// ---------------- LN over 4096 + gates + LSTM update ----------------
__global__ __launch_bounds__(256) void ln_gates(
    const u16* __restrict__ t,       // [B_ROWS][NDIM] bf16
    const float* __restrict__ cell,  // [B_ROWS][H]
    const float* __restrict__ gamma, // [4][H]
    const float* __restrict__ beta,  // [4][H]
    float* __restrict__ out) {       // new_out | new_cell
  const int b   = blockIdx.x;
  const int tid = threadIdx.x;
  const int h0  = tid * 4;

  const u16* trow = t + (long)b * NDIM;
  float v[4][4];
#pragma unroll
  for (int gi = 0; gi < 4; ++gi) {
    u16x4 raw = *(const u16x4*)&trow[gi * H_DIM + h0];
#pragma unroll
    for (int j = 0; j < 4; ++j) v[gi][j] = bf2f(raw[j]);
  }

  float s1 = 0.f, s2 = 0.f;
#pragma unroll
  for (int gi = 0; gi < 4; ++gi)
#pragma unroll
    for (int j = 0; j < 4; ++j) { s1 += v[gi][j]; s2 += v[gi][j] * v[gi][j]; }

#pragma unroll
  for (int m = 32; m; m >>= 1) {
    s1 += __shfl_xor(s1, m);
    s2 += __shfl_xor(s2, m);
  }
  __shared__ float red[2][4];
  const int wave = tid >> 6, lane = tid & 63;
  if (lane == 0) { red[0][wave] = s1; red[1][wave] = s2; }
  __syncthreads();
  s1 = red[0][0] + red[0][1] + red[0][2] + red[0][3];
  s2 = red[1][0] + red[1][1] + red[1][2] + red[1][3];

  const float mean  = s1 * (1.f / (float)NDIM);
  const float var   = s2 * (1.f / (float)NDIM) - mean * mean;
  const float scale = rsqrtf(var + LN_EPSF);

  float hd[4][4];
#pragma unroll
  for (int gi = 0; gi < 4; ++gi) {
    fv4 gm = *(const fv4*)&gamma[gi * H_DIM + h0];
    fv4 bt = *(const fv4*)&beta[gi * H_DIM + h0];
#pragma unroll
    for (int j = 0; j < 4; ++j)
      hd[gi][j] = (v[gi][j] - mean) * scale * gm[j] + bt[j];
  }

  fv4 cv = *(const fv4*)&cell[(long)b * H_DIM + h0];
  fv4 no, nc;
#pragma unroll
  for (int j = 0; j < 4; ++j) {
    float fg = 1.f / (1.f + expf(-hd[0][j]));
    float ig = 1.f / (1.f + expf(-hd[1][j]));
    float og = 1.f / (1.f + expf(-hd[2][j]));
    float hc = 0.5f * hd[3][j] * (1.f + erff(hd[3][j] * 0.70710678118654752f));
    float ncell = fg * cv[j] + ig * hc;
    nc[j] = ncell;
    no[j] = og * ncell;
  }
  *(fv4*)&out[(long)b * H_DIM + h0] = no;
  *(fv4*)&out[(long)B_ROWS * H_DIM + (long)b * H_DIM + h0] = nc;
}

// ---------------- launch ----------------
extern "C" void kernel_launch(void* const* d_in, const int* in_sizes, int n_in,
                              void* d_out, int out_size, void* d_ws, size_t ws_size,
                              hipStream_t stream) {
  const float* x     = (const float*)d_in[0];
  const float* h     = (const float*)d_in[1];
  const float* cell  = (const float*)d_in[2];
  const float* W     = (const float*)d_in[3];
  const float* gamma = (const float*)d_in[4];
  const float* beta  = (const float*)d_in[5];
  float* out = (float*)d_out;

  const size_t cat_bytes = (size_t)B_ROWS * KDIM * sizeof(u16);  // 64 MB
  const size_t w_bytes   = (size_t)NDIM * KDIM * sizeof(u16);    // 16 MB
  const size_t t_bytes   = (size_t)B_ROWS * NDIM * sizeof(u16);  // 128 MB
  if (ws_size < cat_bytes + w_bytes + t_bytes) return;

  uint8_t* ws = (uint8_t*)d_ws;
  u16* catb = (u16*)ws;
  u16* Wb   = (u16*)(ws + cat_bytes);
  u16* tbuf = (u16*)(ws + cat_bytes + w_bytes);

  cast_concat<<<(B_ROWS * (long)KDIM / 8) / 256, 256, 0, stream>>>(x, h, catb);
  cast_plain<<<(NDIM * (long)KDIM / 8) / 256, 256, 0, stream>>>(W, Wb);

  gemm_bt<<<dim3(1024), 512, 0, stream>>>(catb, Wb, tbuf);

  ln_gates<<<B_ROWS, 256, 0, stream>>>(tbuf, cell, gamma, beta, out);
}